// Round 4
// baseline (10.008 us; speedup 1.0000x reference)
//
#include <hip/hip_runtime.h>
#include <cmath>

// HybridQNN fused kernel — closed form of the 4-qubit circuit:
//   h_w = tanh(x . W1[w] + b1[w])          (only wires 0..3 used)
//   u_w = h_w + qw[0,w]
//   z   = cos(qw[2,0]) * cos(u1)*cos(u2)*cos(u3)
//       - sin(qw[2,0]) * cos(qw[1,0])*cos(qw[1,1]) * sin(u0)*sin(u1)
//   t_k = relu(z*W2[k] + b2[k]);  out_j = sum_k t_k*W3[j,k] + b3[j]
//
// R1: 2 samples/thread (float4 store), 2048 blocks (8/CU, max occupancy).
// R2: nontemporal float4 store.
// R4: transcendental minimization —
//     * W1,b1 pre-scaled by 2*log2(e): tanh via native exp2, no extra mul
//     * tanh output + q0 pre-scaled by 1/2pi: native v_sin/v_cos (revolution
//       input), skipping libm range reduction (|rev| <= ~0.26, in HW range)

#define THREADS 256

typedef float f32x4 __attribute__((ext_vector_type(4)));

#define INV2PI  0.15915494309189535f
#define TWOLOG2E 2.885390081777927f

__device__ __forceinline__ void sample_out(
    const float4 xv,
    const float* w1s, const float* bb1s, const float* q0r,
    float cA, float k1,
    const float* w2, const float* bb2, const float* w3a, const float* w3b,
    float b30, float b31, float& o0, float& o1)
{
    float urev[4];
#pragma unroll
    for (int w = 0; w < 4; ++w) {
        // acc_s = 2*log2(e) * (x.W1[w] + b1[w])   (weights pre-scaled)
        float acc = bb1s[w];
        acc = fmaf(xv.x, w1s[4 * w + 0], acc);
        acc = fmaf(xv.y, w1s[4 * w + 1], acc);
        acc = fmaf(xv.z, w1s[4 * w + 2], acc);
        acc = fmaf(xv.w, w1s[4 * w + 3], acc);
        // tanh(a)/2pi = copysign(1/2pi - (2/2pi)*rcp(exp2(|acc_s|)+1), acc)
        const float e = __builtin_amdgcn_exp2f(fabsf(acc));
        const float r = __builtin_amdgcn_rcpf(e + 1.0f);
        const float t = copysignf(fmaf(-2.0f * INV2PI, r, INV2PI), acc);
        urev[w] = t + q0r[w];            // (tanh + q0) / 2pi, |.| <= ~0.26
    }

    const float s0 = __builtin_amdgcn_sinf(urev[0]);
    const float s1 = __builtin_amdgcn_sinf(urev[1]);
    const float c1 = __builtin_amdgcn_cosf(urev[1]);
    const float c2 = __builtin_amdgcn_cosf(urev[2]);
    const float c3 = __builtin_amdgcn_cosf(urev[3]);

    const float z = cA * c1 * c2 * c3 - k1 * s0 * s1;

    o0 = b30; o1 = b31;
#pragma unroll
    for (int k = 0; k < 4; ++k) {
        const float t2 = fmaxf(fmaf(z, w2[k], bb2[k]), 0.0f);
        o0 = fmaf(t2, w3a[k], o0);
        o1 = fmaf(t2, w3b[k], o1);
    }
}

__global__ __launch_bounds__(THREADS) void qnn_fused(
    const float* __restrict__ x,
    const float* __restrict__ W1, const float* __restrict__ b1,
    const float* __restrict__ qw,
    const float* __restrict__ W2, const float* __restrict__ b2,
    const float* __restrict__ W3, const float* __restrict__ b3,
    float* __restrict__ out, int B)
{
    // ---- uniform parameters (uniform addresses -> scalar loads) ----
    float w1s[16], bb1s[4], q0r[4];
#pragma unroll
    for (int j = 0; j < 16; ++j) w1s[j] = W1[j] * TWOLOG2E;
#pragma unroll
    for (int j = 0; j < 4; ++j) { bb1s[j] = b1[j] * TWOLOG2E; q0r[j] = qw[j] * INV2PI; }

    float sA, cA;
    __sincosf(qw[8], &sA, &cA);                           // A = qw[2,0]
    const float k1 = sA * __cosf(qw[4]) * __cosf(qw[5]);  // sinA*cosB0*cosB1

    float w2[4], bb2[4], w3a[4], w3b[4];
#pragma unroll
    for (int j = 0; j < 4; ++j) {
        w2[j]  = W2[j];  bb2[j] = b2[j];
        w3a[j] = W3[j];  w3b[j] = W3[4 + j];
    }
    const float b30 = b3[0], b31 = b3[1];

    const int pair = blockIdx.x * THREADS + threadIdx.x;   // 2 samples per thread
    const int i0 = pair * 2;
    if (i0 + 1 < B) {
        const float4 xa = reinterpret_cast<const float4*>(x)[i0];
        const float4 xb = reinterpret_cast<const float4*>(x)[i0 + 1];
        f32x4 o;
        float oa0, oa1, ob0, ob1;
        sample_out(xa, w1s, bb1s, q0r, cA, k1, w2, bb2, w3a, w3b, b30, b31, oa0, oa1);
        sample_out(xb, w1s, bb1s, q0r, cA, k1, w2, bb2, w3a, w3b, b30, b31, ob0, ob1);
        o.x = oa0; o.y = oa1; o.z = ob0; o.w = ob1;
        __builtin_nontemporal_store(o, reinterpret_cast<f32x4*>(out) + pair);
    } else if (i0 < B) {  // odd-B tail
        const float4 xa = reinterpret_cast<const float4*>(x)[i0];
        float o0, o1;
        sample_out(xa, w1s, bb1s, q0r, cA, k1, w2, bb2, w3a, w3b, b30, b31, o0, o1);
        reinterpret_cast<float2*>(out)[i0] = make_float2(o0, o1);
    }
}

extern "C" void kernel_launch(void* const* d_in, const int* in_sizes, int n_in,
                              void* d_out, int out_size, void* d_ws, size_t ws_size,
                              hipStream_t stream) {
    const float* x  = (const float*)d_in[0];
    const float* W1 = (const float*)d_in[1];
    const float* b1 = (const float*)d_in[2];
    const float* qw = (const float*)d_in[3];
    const float* W2 = (const float*)d_in[4];
    const float* b2 = (const float*)d_in[5];
    const float* W3 = (const float*)d_in[6];
    const float* b3 = (const float*)d_in[7];
    float* out = (float*)d_out;

    const int B = in_sizes[0] / 4;
    const int per_block = THREADS * 2;
    const int blocks = (B + per_block - 1) / per_block;

    qnn_fused<<<blocks, THREADS, 0, stream>>>(x, W1, b1, qw, W2, b2, W3, b3, out, B);
}